// Round 3
// baseline (1041.363 us; speedup 1.0000x reference)
//
#include <hip/hip_runtime.h>
#include <hip/hip_bf16.h>
#include <cstdint>
#include <math.h>

#define TOKENS 4096
#define DMODEL 4096
#define DFF    16384

typedef __attribute__((ext_vector_type(4)))  int i32x4;
typedef __attribute__((ext_vector_type(16))) int i32x16;
typedef __attribute__((address_space(1))) unsigned int glb_u32;
typedef __attribute__((address_space(3))) unsigned int lds_u32;

// ---------------- pack: int32 -> int8 (values already in [-127,127]) ----------------
__global__ void pack_i8_kernel(const int* __restrict__ src, unsigned* __restrict__ dst, long n4) {
    long i = (long)blockIdx.x * blockDim.x + threadIdx.x;
    const long stride = (long)gridDim.x * blockDim.x;
    for (; i < n4; i += stride) {
        const int4 v = ((const int4*)src)[i];
        unsigned p = (unsigned(v.x) & 255u) | ((unsigned(v.y) & 255u) << 8) |
                     ((unsigned(v.z) & 255u) << 16) | ((unsigned(v.w) & 255u) << 24);
        dst[i] = p;
    }
}

__global__ void zero_u32_kernel(unsigned* __restrict__ p, int n) {
    int i = blockIdx.x * blockDim.x + threadIdx.x;
    if (i < n) p[i] = 0u;
}

// ---------------- int8 GEMM, C[row][col] = sum_k A[row][k]*B[col][k] ----------------
// 256x256 tile, BK=128, 8 waves (2M x 4N). Wave tile 128x64 via 4x2 frags of
// 32x32x32 i8 MFMA (acc 16 i32/frag). K-tile = 4 slices of K=32.
// Software pipeline: frag reads issued 2 slices ahead, counted lgkmcnt(12/6),
// 2 barriers per K-tile, stage-ahead-2 with vmcnt(8) (never drained to 0).
//   per tile t (buf=t&1):
//     issue s2(buf);  lgkm(12); MFMA s0
//     issue s3(buf);  lgkm(12); MFMA s1
//                     lgkm(6);  MFMA s2
//     lgkm(0); bar                       // all buf reads complete
//     STAGE A,B (t+2 -> buf)             // 8 gload_lds
//     vmcnt(8); bar                      // tile t+1 resident+visible
//     issue s0,s1 (t+1, buf^1)
//     MFMA s3
// LDS swizzle: chunk ^= (row&7) (16B granule): ds_read_b128 2 lanes/bank (free);
// gload_lds dest linear, source pre-swizzled (verified in R1/R2).
template <int EPI>
__global__ __launch_bounds__(512)
void gemm_i8_kernel(const int8_t* __restrict__ A,
                    const int8_t* __restrict__ B,
                    const int Nout, const int K,
                    const float* __restrict__ scaleA,   // EPI1: in_scale[row]
                    const float* __restrict__ scaleB,   // w1_scale / w2_scale [col]
                    const float* __restrict__ bias,     // b1 / b2 [col]
                    unsigned* __restrict__ rowmax,      // EPI1: atomic out; EPI2: in
                    __hip_bfloat16* __restrict__ aout,  // EPI1: activations out
                    float* __restrict__ out)            // EPI2: final out
{
    __shared__ int8_t As[2][256 * 128];
    __shared__ int8_t Bs[2][256 * 128];

    const int tid  = threadIdx.x;
    const int lane = tid & 63;
    const int w    = tid >> 6;          // 0..7
    const int wm   = w >> 2;            // 0..1  (M half: 128 rows)
    const int wn   = w & 3;             // 0..3  (N quarter: 64 cols)
    const int l31  = lane & 31, l5 = lane >> 5, cx = lane & 7;

    // XCD-chunked bijective block swizzle (nwg % 8 == 0 for both GEMMs here)
    const int gx  = gridDim.x;
    const int nwg = gx * gridDim.y;
    int wg = blockIdx.y * gx + blockIdx.x;
    wg = (wg & 7) * (nwg >> 3) + (wg >> 3);
    const int col0 = (wg % gx) * 256;
    const int row0 = (wg / gx) * 256;

    const int nt = K >> 7;

    // staging: pre-swizzled global source chunk (lane-constant)
    const int g16 = ((lane & 7) ^ (lane >> 3)) << 4;

    // frag ds_read byte offsets: row r, global chunk gc=(s<<1)|l5, c = gc ^ (r&7)
    // A frag m: r = wm*128 + m*32 + l31 ; B frag n: r = wn*64 + n*32 + l31 (r&7==cx)
    const int rbA = ((wm << 7) + l31) << 7;          // + m*32*128
    const int rbB = ((wn << 6) + l31) << 7;          // + n*32*128
#define AOFF(m, s) (rbA + (m) * 4096 + (((((s) << 1) | l5) ^ cx) << 4))
#define BOFF(n, s) (rbB + (n) * 4096 + (((((s) << 1) | l5) ^ cx) << 4))

    i32x4 fA[4][4], fB[4][2];
    i32x16 acc[4][2] = {};

#define READ_SLICE(s, bufi)                                                       \
    {                                                                             \
        _Pragma("unroll")                                                         \
        for (int m_ = 0; m_ < 4; ++m_)                                            \
            fA[s][m_] = *(const i32x4*)(&As[bufi][AOFF(m_, s)]);                  \
        _Pragma("unroll")                                                         \
        for (int n_ = 0; n_ < 2; ++n_)                                            \
            fB[s][n_] = *(const i32x4*)(&Bs[bufi][BOFF(n_, s)]);                  \
    }

#define MFMA_SLICE(s)                                                             \
    {                                                                             \
        __builtin_amdgcn_s_setprio(1);                                            \
        _Pragma("unroll")                                                         \
        for (int m_ = 0; m_ < 4; ++m_)                                            \
            _Pragma("unroll")                                                     \
            for (int n_ = 0; n_ < 2; ++n_)                                        \
                acc[m_][n_] = __builtin_amdgcn_mfma_i32_32x32x32_i8(              \
                    fA[s][m_], fB[s][n_], acc[m_][n_], 0, 0, 0);                  \
        __builtin_amdgcn_s_setprio(0);                                            \
    }

#define STAGE_OP(P, p0q, LDSBUF, t)                                                   \
    {                                                                                 \
        const int k0_ = (t) << 7;                                                     \
        const int8_t* src_ = (P) + (size_t)((p0q) + (w << 3) + (lane >> 3)) * K +     \
                             k0_ + g16;                                               \
        int8_t* dst_ = &LDSBUF[(t) & 1][w << 10];                                     \
        _Pragma("unroll")                                                             \
        for (int u_ = 0; u_ < 4; ++u_)                                                \
            __builtin_amdgcn_global_load_lds((glb_u32*)(src_ + (size_t)(u_ * 64) * K),\
                                             (lds_u32*)(dst_ + u_ * 8192), 16, 0, 0); \
    }

    // prologue: stage tiles 0,1; preload slices 0,1 of tile 0
    STAGE_OP(A, row0, As, 0);
    STAGE_OP(B, col0, Bs, 0);
    STAGE_OP(A, row0, As, 1);
    STAGE_OP(B, col0, Bs, 1);
    asm volatile("s_waitcnt vmcnt(8)" ::: "memory");
    __builtin_amdgcn_s_barrier();
    READ_SLICE(0, 0);
    READ_SLICE(1, 0);

    for (int t = 0; t < nt; ++t) {
        const int buf = t & 1;
        const int tn1 = (t + 1 < nt) ? (t + 1) : (nt - 1);
        const int tn2 = (t + 2 < nt) ? (t + 2) : (nt - 1);

        READ_SLICE(2, buf);
        asm volatile("s_waitcnt lgkmcnt(12)" ::: "memory");
        __builtin_amdgcn_sched_barrier(0);
        MFMA_SLICE(0);

        READ_SLICE(3, buf);
        asm volatile("s_waitcnt lgkmcnt(12)" ::: "memory");
        __builtin_amdgcn_sched_barrier(0);
        MFMA_SLICE(1);

        asm volatile("s_waitcnt lgkmcnt(6)" ::: "memory");
        __builtin_amdgcn_sched_barrier(0);
        MFMA_SLICE(2);

        asm volatile("s_waitcnt lgkmcnt(0)" ::: "memory");
        __builtin_amdgcn_sched_barrier(0);
        __builtin_amdgcn_s_barrier();

        STAGE_OP(A, row0, As, tn2);
        STAGE_OP(B, col0, Bs, tn2);
        asm volatile("s_waitcnt vmcnt(8)" ::: "memory");
        __builtin_amdgcn_s_barrier();

        READ_SLICE(0, tn1 & 1);
        READ_SLICE(1, tn1 & 1);
        MFMA_SLICE(3);
    }
#undef STAGE_OP
#undef READ_SLICE
#undef MFMA_SLICE
#undef AOFF
#undef BOFF

    // C/D frag mapping for 32x32 (measured, dtype-independent):
    //   col = lane&31, row = (reg&3) + 8*(reg>>2) + 4*(lane>>5)
    if (EPI == 1) {
#pragma unroll
        for (int m = 0; m < 4; ++m) {
#pragma unroll
            for (int reg = 0; reg < 16; ++reg) {
                const int grow = row0 + (wm << 7) + m * 32 + (reg & 3) + 8 * (reg >> 2) + 4 * l5;
                const float sa = scaleA[grow];
                float vmax = 0.0f;
                float gl[2];
#pragma unroll
                for (int n = 0; n < 2; ++n) {
                    const int gcol = col0 + (wn << 6) + n * 32 + l31;
                    const float y = (float)acc[m][n][reg] * sa * scaleB[gcol] + bias[gcol];
                    gl[n] = 0.5f * y * (1.0f + erff(y * 0.70710678118654752f));
                    aout[(size_t)grow * DFF + gcol] = __float2bfloat16(gl[n]);
                    vmax = fmaxf(vmax, fabsf(gl[n]));
                }
#pragma unroll
                for (int off = 1; off < 32; off <<= 1)
                    vmax = fmaxf(vmax, __shfl_xor(vmax, off));
                if (l31 == 0) atomicMax(&rowmax[grow], __float_as_uint(vmax));
            }
        }
    } else {
#pragma unroll
        for (int m = 0; m < 4; ++m) {
#pragma unroll
            for (int reg = 0; reg < 16; ++reg) {
                const int grow = row0 + (wm << 7) + m * 32 + (reg & 3) + 8 * (reg >> 2) + 4 * l5;
                const float s2 = fmaxf(__uint_as_float(rowmax[grow]) * (1.0f / 127.0f), 1e-8f);
#pragma unroll
                for (int n = 0; n < 2; ++n) {
                    const int gcol = col0 + (wn << 6) + n * 32 + l31;
                    out[(size_t)grow * Nout + gcol] =
                        (float)acc[m][n][reg] * s2 * scaleB[gcol] + bias[gcol];
                }
            }
        }
    }
}

// ---------------- dynamic requant: q2 = clip(rint(a / s2), -128, 127) ----------------
__global__ void quant_kernel(const unsigned short* __restrict__ a,  // bf16 bits
                             const unsigned* __restrict__ rowmax,
                             int8_t* __restrict__ q2)
{
    const size_t nvec = (size_t)TOKENS * DFF / 8;
    size_t i = (size_t)blockIdx.x * blockDim.x + threadIdx.x;
    const size_t stride = (size_t)gridDim.x * blockDim.x;
    for (; i < nvec; i += stride) {
        const size_t e0 = i * 8;
        const int n = (int)(e0 >> 14);  // / DFF
        const float s2 = fmaxf(__uint_as_float(rowmax[n]) * (1.0f / 127.0f), 1e-8f);
        const float inv = 1.0f / s2;
        const uint4 v = *(const uint4*)(a + e0);
        const unsigned words[4] = {v.x, v.y, v.z, v.w};
        int qi[8];
#pragma unroll
        for (int j = 0; j < 4; ++j) {
            const float f0 = __uint_as_float((words[j] & 0xffffu) << 16);
            const float f1 = __uint_as_float(words[j] & 0xffff0000u);
            qi[2 * j]     = (int)fminf(fmaxf(rintf(f0 * inv), -128.0f), 127.0f);
            qi[2 * j + 1] = (int)fminf(fmaxf(rintf(f1 * inv), -128.0f), 127.0f);
        }
        const unsigned p0 = (unsigned(qi[0]) & 255u) | ((unsigned(qi[1]) & 255u) << 8) |
                            ((unsigned(qi[2]) & 255u) << 16) | ((unsigned(qi[3]) & 255u) << 24);
        const unsigned p1 = (unsigned(qi[4]) & 255u) | ((unsigned(qi[5]) & 255u) << 8) |
                            ((unsigned(qi[6]) & 255u) << 16) | ((unsigned(qi[7]) & 255u) << 24);
        ((uint2*)q2)[i] = make_uint2(p0, p1);
    }
}

extern "C" void kernel_launch(void* const* d_in, const int* in_sizes, int n_in,
                              void* d_out, int out_size, void* d_ws, size_t ws_size,
                              hipStream_t stream) {
    const int*   q_in     = (const int*)d_in[0];
    const float* in_scale = (const float*)d_in[1];
    const int*   w1_q     = (const int*)d_in[2];
    const float* w1_scale = (const float*)d_in[3];
    const float* b1       = (const float*)d_in[4];
    const int*   w2_q     = (const int*)d_in[5];
    const float* w2_scale = (const float*)d_in[6];
    const float* b2       = (const float*)d_in[7];
    float* out = (float*)d_out;

    // workspace layout (total 336 MiB + 16 KiB)
    char* ws = (char*)d_ws;
    int8_t* A1 = (int8_t*)(ws);                                  //  16 MiB  q_in int8
    int8_t* W1 = (int8_t*)(ws + (size_t)16  * 1048576);          //  64 MiB
    int8_t* W2 = (int8_t*)(ws + (size_t)80  * 1048576);          //  64 MiB
    int8_t* Q2 = (int8_t*)(ws + (size_t)144 * 1048576);          //  64 MiB
    unsigned short* ABUF = (unsigned short*)(ws + (size_t)208 * 1048576);  // 128 MiB bf16 acts
    unsigned* ROWMAX = (unsigned*)(ws + (size_t)336 * 1048576);  //  16 KiB

    zero_u32_kernel<<<dim3(16), dim3(256), 0, stream>>>(ROWMAX, TOKENS);
    pack_i8_kernel<<<dim3(1024), dim3(256), 0, stream>>>(q_in, (unsigned*)A1, (long)TOKENS * DMODEL / 4);
    pack_i8_kernel<<<dim3(4096), dim3(256), 0, stream>>>(w1_q, (unsigned*)W1, (long)DFF * DMODEL / 4);
    pack_i8_kernel<<<dim3(4096), dim3(256), 0, stream>>>(w2_q, (unsigned*)W2, (long)DMODEL * DFF / 4);

    gemm_i8_kernel<1><<<dim3(DFF / 256, TOKENS / 256), dim3(512), 0, stream>>>(
        A1, W1, DFF, DMODEL, in_scale, w1_scale, b1, ROWMAX,
        (__hip_bfloat16*)ABUF, nullptr);

    quant_kernel<<<dim3(4096), dim3(256), 0, stream>>>(ABUF, ROWMAX, Q2);

    gemm_i8_kernel<2><<<dim3(DMODEL / 256, TOKENS / 256), dim3(512), 0, stream>>>(
        Q2, W2, DMODEL, DFF, nullptr, w2_scale, b2, ROWMAX,
        nullptr, out);
}

// Round 4
// 965.261 us; speedup vs baseline: 1.0788x; 1.0788x over previous
//
#include <hip/hip_runtime.h>
#include <hip/hip_bf16.h>
#include <cstdint>
#include <math.h>

#define TOKENS 4096
#define DMODEL 4096
#define DFF    16384

typedef __attribute__((ext_vector_type(4))) int i32x4;
typedef __attribute__((address_space(1))) unsigned int glb_u32;
typedef __attribute__((address_space(3))) unsigned int lds_u32;

// ---------------- pack: int32 -> int8 (values already in [-127,127]) ----------------
__global__ void pack_i8_kernel(const int* __restrict__ src, unsigned* __restrict__ dst, long n4) {
    long i = (long)blockIdx.x * blockDim.x + threadIdx.x;
    const long stride = (long)gridDim.x * blockDim.x;
    for (; i < n4; i += stride) {
        const int4 v = ((const int4*)src)[i];
        unsigned p = (unsigned(v.x) & 255u) | ((unsigned(v.y) & 255u) << 8) |
                     ((unsigned(v.z) & 255u) << 16) | ((unsigned(v.w) & 255u) << 24);
        dst[i] = p;
    }
}

__global__ void zero_u32_kernel(unsigned* __restrict__ p, int n) {
    int i = blockIdx.x * blockDim.x + threadIdx.x;
    if (i < n) p[i] = 0u;
}

// ---------------- int8 GEMM, C[row][col] = sum_k A[row][k]*B[col][k] ----------------
// 256x256 tile, BK=128, 8 waves (2M x 4N), wave tile 128x64 via 8x4 frags of
// 16x16x64 i8 MFMA (R2-proven layout & swizzle). m201-style phases: per K-tile t
// 4 quadrant phases {m0-3 kk0, m4-7 kk0, m0-3 kk1, m4-7 kk1}, each:
//   ds_reads (this quadrant) ; stage 2 units (tile t+1 -> buf^1) ;
//   sched_barrier ; s_barrier ; lgkm(0) ; setprio1 ; 16 MFMA ; setprio0 ;
//   [vmcnt(2) at P0 and P3] ; s_barrier
// LDS latency hides under barrier #1 while other waves run MFMA.
// Stage order B0B1,B2B3,A0A2,A1A3 (units = 64-row spans). vmcnt audit:
//   end-P0: outstanding {A1,A3(t), B0,B1(t+1)} -> vmcnt(2) completes A1,A3
//           (needed by P1's m4-7 reads).
//   end-P3: outstanding {B0..B3,A0,A2,A1,A3 (t+1)} -> vmcnt(2) completes the
//           6 units P0(t+1) reads (A0,A2,B*); A1,A3 stay in flight.
// Last tile stages itself (same bytes -> benign race, counts unchanged).
template <int EPI>
__global__ __launch_bounds__(512)
void gemm_i8_kernel(const int8_t* __restrict__ A,
                    const int8_t* __restrict__ B,
                    const int Nout, const int K,
                    const float* __restrict__ scaleA,   // EPI1: in_scale[row]
                    const float* __restrict__ scaleB,   // w1_scale / w2_scale [col]
                    const float* __restrict__ bias,     // b1 / b2 [col]
                    unsigned* __restrict__ rowmax,      // EPI1: atomic out; EPI2: in
                    __hip_bfloat16* __restrict__ aout,  // EPI1: activations out
                    float* __restrict__ out)            // EPI2: final out
{
    __shared__ int8_t As[2][256 * 128];
    __shared__ int8_t Bs[2][256 * 128];

    const int tid  = threadIdx.x;
    const int lane = tid & 63;
    const int w    = tid >> 6;          // 0..7
    const int wm   = w >> 2;            // 0..1  (M half: 128 rows)
    const int wn   = w & 3;             // 0..3  (N quarter: 64 cols)
    const int l15  = lane & 15, l4 = lane >> 4;

    // XCD-chunked bijective block swizzle (nwg % 8 == 0 for both GEMMs here)
    const int gx  = gridDim.x;
    const int nwg = gx * gridDim.y;
    int wg = blockIdx.y * gx + blockIdx.x;
    wg = (wg & 7) * (nwg >> 3) + (wg >> 3);
    const int col0 = (wg % gx) * 256;
    const int row0 = (wg / gx) * 256;

    const int nt = K >> 7;

    // staging: pre-swizzled global source chunk (lane-constant); proven R1/R2
    const int g16 = ((lane & 7) ^ (lane >> 3)) << 4;

    // frag ds_read addressing (R2-proven, zero-conflict):
    // row r, chunk c = (kk*4+l4) ^ (r&7); r&7 == l15&7
    const int rbA = (((wm << 7) + l15) << 7);        // byte base; + m*2048
    const int rbB = (((wn << 6) + l15) << 7);        // byte base; + n*2048
    const int c0  = (l4 ^ (l15 & 7)) << 4;           // kk0 chunk byte; kk1 = c0 ^ 64

    i32x4 fAlo[4], fAhi[4], fB[4];
    i32x4 acc[8][4] = {};

    // one 8KB unit (64 rows) of operand P staged from rows p0q+u*64.. into LDS buf
#define STAGE_UNIT(P, p0q, LDSARR, bufi, t, u)                                        \
    {                                                                                 \
        const int8_t* src_ = (P) + (size_t)((p0q) + (u) * 64 + (w << 3) +             \
                             (lane >> 3)) * K + ((t) << 7) + g16;                     \
        int8_t* dst_ = &LDSARR[bufi][(u) * 8192 + (w << 10)];                         \
        __builtin_amdgcn_global_load_lds((glb_u32*)src_, (lds_u32*)dst_, 16, 0, 0);   \
    }

#define MFMA_Q(FA, MB)                                                                \
    {                                                                                 \
        __builtin_amdgcn_s_setprio(1);                                                \
        _Pragma("unroll")                                                             \
        for (int m_ = 0; m_ < 4; ++m_)                                                \
            _Pragma("unroll")                                                         \
            for (int n_ = 0; n_ < 4; ++n_)                                            \
                acc[(MB) + m_][n_] = __builtin_amdgcn_mfma_i32_16x16x64_i8(           \
                    FA[m_], fB[n_], acc[(MB) + m_][n_], 0, 0, 0);                     \
        __builtin_amdgcn_s_setprio(0);                                                \
    }

    // prologue: stage all 8 units of tile 0 into buf 0, drain, barrier
#pragma unroll
    for (int u = 0; u < 4; ++u) STAGE_UNIT(B, col0, Bs, 0, 0, u);
#pragma unroll
    for (int u = 0; u < 4; ++u) STAGE_UNIT(A, row0, As, 0, 0, u);
    asm volatile("s_waitcnt vmcnt(0)" ::: "memory");
    __builtin_amdgcn_s_barrier();

    for (int t = 0; t < nt; ++t) {
        const int buf  = t & 1;
        const int nbuf = buf ^ 1;
        const int tn   = (t + 1 < nt) ? (t + 1) : (nt - 1);

        // ---- P0: quadrant m0-3 kk0 ----
#pragma unroll
        for (int m = 0; m < 4; ++m)
            fAlo[m] = *(const i32x4*)(&As[buf][rbA + m * 2048 + c0]);
#pragma unroll
        for (int n = 0; n < 4; ++n)
            fB[n] = *(const i32x4*)(&Bs[buf][rbB + n * 2048 + c0]);
        STAGE_UNIT(B, col0, Bs, nbuf, tn, 0);
        STAGE_UNIT(B, col0, Bs, nbuf, tn, 1);
        __builtin_amdgcn_sched_barrier(0);
        __builtin_amdgcn_s_barrier();
        asm volatile("s_waitcnt lgkmcnt(0)" ::: "memory");
        __builtin_amdgcn_sched_barrier(0);
        MFMA_Q(fAlo, 0);
        asm volatile("s_waitcnt vmcnt(2)" ::: "memory");
        __builtin_amdgcn_s_barrier();

        // ---- P1: quadrant m4-7 kk0 ----
#pragma unroll
        for (int m = 0; m < 4; ++m)
            fAhi[m] = *(const i32x4*)(&As[buf][rbA + (m + 4) * 2048 + c0]);
        STAGE_UNIT(B, col0, Bs, nbuf, tn, 2);
        STAGE_UNIT(B, col0, Bs, nbuf, tn, 3);
        __builtin_amdgcn_sched_barrier(0);
        __builtin_amdgcn_s_barrier();
        asm volatile("s_waitcnt lgkmcnt(0)" ::: "memory");
        __builtin_amdgcn_sched_barrier(0);
        MFMA_Q(fAhi, 4);
        __builtin_amdgcn_s_barrier();

        // ---- P2: quadrant m0-3 kk1 ----
#pragma unroll
        for (int m = 0; m < 4; ++m)
            fAlo[m] = *(const i32x4*)(&As[buf][rbA + m * 2048 + (c0 ^ 64)]);
#pragma unroll
        for (int n = 0; n < 4; ++n)
            fB[n] = *(const i32x4*)(&Bs[buf][rbB + n * 2048 + (c0 ^ 64)]);
        STAGE_UNIT(A, row0, As, nbuf, tn, 0);
        STAGE_UNIT(A, row0, As, nbuf, tn, 2);
        __builtin_amdgcn_sched_barrier(0);
        __builtin_amdgcn_s_barrier();
        asm volatile("s_waitcnt lgkmcnt(0)" ::: "memory");
        __builtin_amdgcn_sched_barrier(0);
        MFMA_Q(fAlo, 0);
        __builtin_amdgcn_s_barrier();

        // ---- P3: quadrant m4-7 kk1 ----
#pragma unroll
        for (int m = 0; m < 4; ++m)
            fAhi[m] = *(const i32x4*)(&As[buf][rbA + (m + 4) * 2048 + (c0 ^ 64)]);
        STAGE_UNIT(A, row0, As, nbuf, tn, 1);
        STAGE_UNIT(A, row0, As, nbuf, tn, 3);
        __builtin_amdgcn_sched_barrier(0);
        __builtin_amdgcn_s_barrier();
        asm volatile("s_waitcnt lgkmcnt(0)" ::: "memory");
        __builtin_amdgcn_sched_barrier(0);
        MFMA_Q(fAhi, 4);
        asm volatile("s_waitcnt vmcnt(2)" ::: "memory");
        __builtin_amdgcn_s_barrier();
    }
#undef STAGE_UNIT
#undef MFMA_Q

    // C/D frag mapping (gfx950, dtype-independent): col = lane&15, row = (lane>>4)*4 + reg
    if (EPI == 1) {
#pragma unroll
        for (int m = 0; m < 8; ++m) {
#pragma unroll
            for (int reg = 0; reg < 4; ++reg) {
                const int grow = row0 + (wm << 7) + m * 16 + l4 * 4 + reg;
                const float sa = scaleA[grow];
                float vmax = 0.0f;
#pragma unroll
                for (int n = 0; n < 4; ++n) {
                    const int gcol = col0 + (wn << 6) + n * 16 + l15;
                    const float y = (float)acc[m][n][reg] * sa * scaleB[gcol] + bias[gcol];
                    const float gl = 0.5f * y * (1.0f + erff(y * 0.70710678118654752f));
                    aout[(size_t)grow * DFF + gcol] = __float2bfloat16(gl);
                    vmax = fmaxf(vmax, fabsf(gl));
                }
#pragma unroll
                for (int off = 1; off < 16; off <<= 1)
                    vmax = fmaxf(vmax, __shfl_xor(vmax, off));
                if (l15 == 0) atomicMax(&rowmax[grow], __float_as_uint(vmax));
            }
        }
    } else {
#pragma unroll
        for (int m = 0; m < 8; ++m) {
#pragma unroll
            for (int reg = 0; reg < 4; ++reg) {
                const int grow = row0 + (wm << 7) + m * 16 + l4 * 4 + reg;
                const float s2 = fmaxf(__uint_as_float(rowmax[grow]) * (1.0f / 127.0f), 1e-8f);
#pragma unroll
                for (int n = 0; n < 4; ++n) {
                    const int gcol = col0 + (wn << 6) + n * 16 + l15;
                    out[(size_t)grow * Nout + gcol] =
                        (float)acc[m][n][reg] * s2 * scaleB[gcol] + bias[gcol];
                }
            }
        }
    }
}

// ---------------- dynamic requant: q2 = clip(rint(a / s2), -128, 127) ----------------
__global__ void quant_kernel(const unsigned short* __restrict__ a,  // bf16 bits
                             const unsigned* __restrict__ rowmax,
                             int8_t* __restrict__ q2)
{
    const size_t nvec = (size_t)TOKENS * DFF / 8;
    size_t i = (size_t)blockIdx.x * blockDim.x + threadIdx.x;
    const size_t stride = (size_t)gridDim.x * blockDim.x;
    for (; i < nvec; i += stride) {
        const size_t e0 = i * 8;
        const int n = (int)(e0 >> 14);  // / DFF
        const float s2 = fmaxf(__uint_as_float(rowmax[n]) * (1.0f / 127.0f), 1e-8f);
        const float inv = 1.0f / s2;
        const uint4 v = *(const uint4*)(a + e0);
        const unsigned words[4] = {v.x, v.y, v.z, v.w};
        int qi[8];
#pragma unroll
        for (int j = 0; j < 4; ++j) {
            const float f0 = __uint_as_float((words[j] & 0xffffu) << 16);
            const float f1 = __uint_as_float(words[j] & 0xffff0000u);
            qi[2 * j]     = (int)fminf(fmaxf(rintf(f0 * inv), -128.0f), 127.0f);
            qi[2 * j + 1] = (int)fminf(fmaxf(rintf(f1 * inv), -128.0f), 127.0f);
        }
        const unsigned p0 = (unsigned(qi[0]) & 255u) | ((unsigned(qi[1]) & 255u) << 8) |
                            ((unsigned(qi[2]) & 255u) << 16) | ((unsigned(qi[3]) & 255u) << 24);
        const unsigned p1 = (unsigned(qi[4]) & 255u) | ((unsigned(qi[5]) & 255u) << 8) |
                            ((unsigned(qi[6]) & 255u) << 16) | ((unsigned(qi[7]) & 255u) << 24);
        ((uint2*)q2)[i] = make_uint2(p0, p1);
    }
}

extern "C" void kernel_launch(void* const* d_in, const int* in_sizes, int n_in,
                              void* d_out, int out_size, void* d_ws, size_t ws_size,
                              hipStream_t stream) {
    const int*   q_in     = (const int*)d_in[0];
    const float* in_scale = (const float*)d_in[1];
    const int*   w1_q     = (const int*)d_in[2];
    const float* w1_scale = (const float*)d_in[3];
    const float* b1       = (const float*)d_in[4];
    const int*   w2_q     = (const int*)d_in[5];
    const float* w2_scale = (const float*)d_in[6];
    const float* b2       = (const float*)d_in[7];
    float* out = (float*)d_out;

    // workspace layout (total 336 MiB + 16 KiB)
    char* ws = (char*)d_ws;
    int8_t* A1 = (int8_t*)(ws);                                  //  16 MiB  q_in int8
    int8_t* W1 = (int8_t*)(ws + (size_t)16  * 1048576);          //  64 MiB
    int8_t* W2 = (int8_t*)(ws + (size_t)80  * 1048576);          //  64 MiB
    int8_t* Q2 = (int8_t*)(ws + (size_t)144 * 1048576);          //  64 MiB
    unsigned short* ABUF = (unsigned short*)(ws + (size_t)208 * 1048576);  // 128 MiB bf16 acts
    unsigned* ROWMAX = (unsigned*)(ws + (size_t)336 * 1048576);  //  16 KiB

    zero_u32_kernel<<<dim3(16), dim3(256), 0, stream>>>(ROWMAX, TOKENS);
    pack_i8_kernel<<<dim3(1024), dim3(256), 0, stream>>>(q_in, (unsigned*)A1, (long)TOKENS * DMODEL / 4);
    pack_i8_kernel<<<dim3(4096), dim3(256), 0, stream>>>(w1_q, (unsigned*)W1, (long)DFF * DMODEL / 4);
    pack_i8_kernel<<<dim3(4096), dim3(256), 0, stream>>>(w2_q, (unsigned*)W2, (long)DMODEL * DFF / 4);

    gemm_i8_kernel<1><<<dim3(DFF / 256, TOKENS / 256), dim3(512), 0, stream>>>(
        A1, W1, DFF, DMODEL, in_scale, w1_scale, b1, ROWMAX,
        (__hip_bfloat16*)ABUF, nullptr);

    quant_kernel<<<dim3(4096), dim3(256), 0, stream>>>(ABUF, ROWMAX, Q2);

    gemm_i8_kernel<2><<<dim3(DMODEL / 256, TOKENS / 256), dim3(512), 0, stream>>>(
        Q2, W2, DMODEL, DFF, nullptr, w2_scale, b2, ROWMAX,
        nullptr, out);
}